// Round 9
// baseline (36.374 us; speedup 1.0000x reference)
//
#include <hip/hip_runtime.h>
#include <hip/hip_bf16.h>

#define BB 4
#define NN 512
#define CC 32
#define KK 4      // K+1
#define HH 4
#define AOUT 256

// ws float-index offsets (si/sj)
#define WS_SI_F   0
#define WS_SII_F  (BB*NN*HH)
#define WS_SJR_F  (2*BB*NN*HH)
#define WS_SJI_F  (3*BB*NN*HH)
// ws byte offsets
#define XT_BASE   131072         // bf16 X tiles [part][b][jb16] x 2048 B
#define LX_BASE   393216         // bf16 LX [bn] x 2048 B   (4 MB)
#define BRE_BASE  4587520        // bf16 B_re fragments, 128 KB
#define BIM_BASE  4718592        // bf16 B_im fragments, 128 KB

typedef __attribute__((ext_vector_type(8))) short bf16x8;
typedef __attribute__((ext_vector_type(4))) float f32x4;

__device__ __forceinline__ ushort f2bfu(float f){
    union { __hip_bfloat16 h; ushort u; } cv;
    cv.h = __float2bfloat16(f);
    return cv.u;
}
__device__ __forceinline__ short f2bfs(float f){ return (short)f2bfu(f); }
__device__ __forceinline__ float bfu2f(unsigned int u){ return __uint_as_float(u << 16); }
__device__ __forceinline__ unsigned int pk2(float lo, float hi){
    return (unsigned int)f2bfu(lo) | ((unsigned int)f2bfu(hi) << 16);
}

// ---------------------------------------------------------------------------
// Fused prep kernel: grid 96 x 256  (unchanged from round 5)
// ---------------------------------------------------------------------------
__global__ __launch_bounds__(256) void prep_kernel(
    const float* __restrict__ Xr, const float* __restrict__ Xi,
    const float* __restrict__ AWr, const float* __restrict__ AWi,
    const float* __restrict__ Wr, const float* __restrict__ Wi,
    float* __restrict__ ws, char* __restrict__ wsB)
{
    const int blk = blockIdx.x;
    const int t = threadIdx.x;

    if (blk < 32) {
        const int row = blk*64 + (t >> 2);
        const int q = t & 3;
        const float* xr = Xr + (size_t)row*CC + q*8;
        const float* xi = Xi + (size_t)row*CC + q*8;
        float4 xr4[2], xi4[2];
        xr4[0] = *(const float4*)xr;  xr4[1] = *(const float4*)(xr + 4);
        xi4[0] = *(const float4*)xi;  xi4[1] = *(const float4*)(xi + 4);

        float sir[HH] = {0,0,0,0}, sii[HH] = {0,0,0,0};
        float sjr[HH] = {0,0,0,0}, sji[HH] = {0,0,0,0};
        #pragma unroll
        for (int e = 0; e < 8; ++e) {
            float xrc = ((const float*)&xr4[e>>2])[e & 3];
            float xic = ((const float*)&xi4[e>>2])[e & 3];
            int c = q*8 + e;
            float4 w1r = *(const float4*)(AWr + c*HH);
            float4 w1i = *(const float4*)(AWi + c*HH);
            float4 w2r = *(const float4*)(AWr + (CC + c)*HH);
            float4 w2i = *(const float4*)(AWi + (CC + c)*HH);
            #pragma unroll
            for (int h = 0; h < HH; ++h) {
                float r1 = ((const float*)&w1r)[h], i1 = ((const float*)&w1i)[h];
                float r2 = ((const float*)&w2r)[h], i2 = ((const float*)&w2i)[h];
                sir[h] = fmaf(xrc, r1, fmaf(-xic, i1, sir[h]));
                sii[h] = fmaf(xrc, i1, fmaf( xic, r1, sii[h]));
                sjr[h] = fmaf(xrc, r2, fmaf(-xic, i2, sjr[h]));
                sji[h] = fmaf(xrc, i2, fmaf( xic, r2, sji[h]));
            }
        }
        float A[HH], Bv[HH];
        #pragma unroll
        for (int h = 0; h < HH; ++h) {
            float sendA = (q & 1) ? sir[h] : sii[h];
            float keepA = (q & 1) ? sii[h] : sir[h];
            A[h] = keepA + __shfl_xor(sendA, 1);
            float sendB = (q & 1) ? sjr[h] : sji[h];
            float keepB = (q & 1) ? sji[h] : sjr[h];
            Bv[h] = keepB + __shfl_xor(sendB, 1);
        }
        float tot[HH];
        #pragma unroll
        for (int h = 0; h < HH; ++h) {
            float send = (q & 2) ? A[h] : Bv[h];
            float keep = (q & 2) ? Bv[h] : A[h];
            tot[h] = keep + __shfl_xor(send, 2);
        }
        float4 v = make_float4(tot[0], tot[1], tot[2], tot[3]);
        *(float4*)(ws + (size_t)q*(BB*NN*HH) + (size_t)row*HH) = v;
    } else if (blk < 64) {
        int bid = (blk - 32)*4 + (t >> 6);   // 0..127: part*64 + b*16 + jb
        int part = bid >> 6, b = (bid >> 4) & 3, jb = bid & 15;
        const float* X = part ? Xi : Xr;
        int lane = t & 63;
        int c = lane & 31, jh = lane >> 5;

        unsigned int w[8];
        #pragma unroll
        for (int qq = 0; qq < 8; ++qq) {
            int ji = jh*16 + qq*2;
            float f0 = X[((size_t)b*NN + jb*32 + ji  )*CC + c];
            float f1 = X[((size_t)b*NN + jb*32 + ji+1)*CC + c];
            w[qq] = (unsigned int)f2bfu(f0) | ((unsigned int)f2bfu(f1) << 16);
        }
        char* tile = wsB + XT_BASE + (((size_t)(part*4 + b)*16 + jb) * 2048);
        uint4* dst = (uint4*)(tile + c*64 + jh*32);
        dst[0] = make_uint4(w[0], w[1], w[2], w[3]);
        dst[1] = make_uint4(w[4], w[5], w[6], w[7]);
    } else {
        int idx = (blk - 64)*256 + t;        // 0..8191
        int l  = idx & 63;
        int s  = (idx >> 6) & 7;
        int Nt = (idx >> 9) & 3;
        int h  = idx >> 11;
        int p = Nt*16 + (l & 15), o = p*4 + h;
        int e8 = (l >> 4) * 8;
        unsigned int re_w[4], im_w[4];
        #pragma unroll
        for (int qq = 0; qq < 4; ++qq) {
            unsigned int rw = 0, iw = 0;
            #pragma unroll
            for (int half = 0; half < 2; ++half) {
                int kpos = s*32 + e8 + qq*2 + half;
                int ri = kpos >> 7, kk = (kpos >> 5) & 3, c = kpos & 31;
                float wr = Wr[(size_t)(kk*CC + c)*AOUT + o];
                float wi = Wi[(size_t)(kk*CC + c)*AOUT + o];
                unsigned int vre = f2bfu(ri ? -wi : wr);
                unsigned int vim = f2bfu(ri ?  wr : wi);
                rw |= vre << (16*half);
                iw |= vim << (16*half);
            }
            re_w[qq] = rw; im_w[qq] = iw;
        }
        size_t fo = ((size_t)((h*4 + Nt)*8 + s))*1024 + (size_t)l*16;
        *(uint4*)(wsB + BRE_BASE + fo) = make_uint4(re_w[0], re_w[1], re_w[2], re_w[3]);
        *(uint4*)(wsB + BIM_BASE + fo) = make_uint4(im_w[0], im_w[1], im_w[2], im_w[3]);
    }
}

// ---------------------------------------------------------------------------
// Main kernel: ONE WAVE (64 thr) per (b,n). Barrier-free except one sync.
//  thread t owns j in [8t, 8t+8): loads all 8 L rows there (mask in-regs),
//  scores+exp in regs, shuffle-only softmax, write Lf/aw bf16 to LDS,
//  ONE __syncthreads, 16 MFMA steps, reduce-free epilogue.
//  LDS row stride 544 ushorts (1088 B -> <=2-way bank alias on b128 reads).
// ---------------------------------------------------------------------------
__global__ __launch_bounds__(64) void cheb_main_kernel(
    const float* __restrict__ Lr_g, const float* __restrict__ Li_g,
    const float* __restrict__ abr, const float* __restrict__ abi,
    const float* __restrict__ par, const float* __restrict__ pai,
    const float* __restrict__ ws, char* __restrict__ wsB)
{
    __shared__ ushort Lf[8][544];       // 8704 B  (rows 0-3 Lr, 4-7 Li)
    __shared__ ushort awB[HH][544];     // 4352 B  bf16 exp values

    const int bn = blockIdx.x;
    const int b = bn >> 9;
    const int n = bn & (NN - 1);
    const int t = threadIdx.x;          // 0..63
    const int jw = 8*t;

    // ---- issue L loads (HBM, longest latency) ----
    float4 va[8], vb[8];
    #pragma unroll
    for (int it = 0; it < 8; ++it) {
        const float* src = (it & 4) ? Li_g : Lr_g;
        size_t goff = (((size_t)b*KK + (it & 3))*NN + n)*NN + jw;
        va[it] = *(const float4*)(src + goff);
        vb[it] = *(const float4*)(src + goff + 4);
    }
    // ---- issue sj/si loads ----
    float4 sjr[8], sji[8];
    #pragma unroll
    for (int e = 0; e < 8; ++e) {
        sjr[e] = *(const float4*)(ws + WS_SJR_F + ((size_t)b*NN + jw + e)*HH);
        sji[e] = *(const float4*)(ws + WS_SJI_F + ((size_t)b*NN + jw + e)*HH);
    }
    const float4 si_r4 = *(const float4*)(ws + WS_SI_F  + (size_t)bn*HH);
    const float4 si_i4 = *(const float4*)(ws + WS_SII_F + (size_t)bn*HH);
    const float a_r = par[0], a_i = pai[0];

    // ---- P1: stage L as bf16, mask thread-local ----
    float am8[8] = {0.f,0.f,0.f,0.f,0.f,0.f,0.f,0.f};
    #pragma unroll
    for (int it = 0; it < 8; ++it) {
        if (it < 4) {
            am8[0] += fabsf(va[it].x); am8[1] += fabsf(va[it].y);
            am8[2] += fabsf(va[it].z); am8[3] += fabsf(va[it].w);
            am8[4] += fabsf(vb[it].x); am8[5] += fabsf(vb[it].y);
            am8[6] += fabsf(vb[it].z); am8[7] += fabsf(vb[it].w);
        }
        uint4 W;
        W.x = pk2(va[it].x, va[it].y);
        W.y = pk2(va[it].z, va[it].w);
        W.z = pk2(vb[it].x, vb[it].y);
        W.w = pk2(vb[it].z, vb[it].w);
        *(uint4*)&Lf[it][jw] = W;
    }

    // ---- P2: scores + masked + shuffle softmax (all in registers) ----
    float sir[HH], sii[HH];
    #pragma unroll
    for (int h = 0; h < HH; ++h) {
        sir[h] = ((const float*)&si_r4)[h] + abr[h];
        sii[h] = ((const float*)&si_i4)[h] + abi[h];
    }
    const float NEG = -1e9f;
    const float MASKED = NEG*NEG + NEG*NEG;

    float sc[8][HH];
    float pm[HH] = {-INFINITY, -INFINITY, -INFINITY, -INFINITY};
    #pragma unroll
    for (int e = 0; e < 8; ++e) {
        bool msk = am8[e] > 1e-9f;
        const float* sjrp = (const float*)&sjr[e];
        const float* sjip = (const float*)&sji[e];
        #pragma unroll
        for (int h = 0; h < HH; ++h) {
            float sr = sir[h] + sjrp[h];
            sr = sr >= 0.f ? sr : a_r * sr;
            float sv = sii[h] + sjip[h];
            sv = sv >= 0.f ? sv : a_i * sv;
            float val = msk ? (sr*sr + sv*sv) : MASKED;
            sc[e][h] = val;
            pm[h] = fmaxf(pm[h], val);
        }
    }
    #pragma unroll
    for (int h = 0; h < HH; ++h) {
        #pragma unroll
        for (int off = 32; off > 0; off >>= 1)
            pm[h] = fmaxf(pm[h], __shfl_xor(pm[h], off));
    }
    float ps[HH];
    #pragma unroll
    for (int h = 0; h < HH; ++h) {
        float ev[8];
        #pragma unroll
        for (int e = 0; e < 8; ++e) ev[e] = __expf(sc[e][h] - pm[h]);
        uint4 W;
        W.x = pk2(ev[0], ev[1]);
        W.y = pk2(ev[2], ev[3]);
        W.z = pk2(ev[4], ev[5]);
        W.w = pk2(ev[6], ev[7]);
        *(uint4*)&awB[h][jw] = W;
        ps[h] = ((ev[0]+ev[1]) + (ev[2]+ev[3])) + ((ev[4]+ev[5]) + (ev[6]+ev[7]));
        #pragma unroll
        for (int off = 32; off > 0; off >>= 1)
            ps[h] += __shfl_xor(ps[h], off);
    }
    float inv[HH];
    #pragma unroll
    for (int h = 0; h < HH; ++h) inv[h] = 1.0f / ps[h];

    __syncthreads();                    // single-wave: just a waitcnt-fence

    // ---- P3: 16 MFMA steps over full j range ----
    const int r_a = t & 15;             // A row = k*4+h
    const int jg  = t >> 4;
    const int k_a = r_a >> 2, h_a = r_a & 3;

    const char* xtR = wsB + XT_BASE + ((size_t)(0*4 + b)*16)*2048;
    const char* xtI = wsB + XT_BASE + ((size_t)(4   + b)*16)*2048;
    const int bofs = (t & 15)*64 + jg*16;

    f32x4 acc[8];                       // RR0 RR1 II0 II1 RI0 RI1 IR0 IR1
    #pragma unroll
    for (int a = 0; a < 8; ++a) acc[a] = (f32x4){0.f,0.f,0.f,0.f};

#define LB(s, BR0,BR1,BI0,BI1) do {                                           \
        BR0 = *(const bf16x8*)(xtR + (s)*2048 +        bofs);                 \
        BR1 = *(const bf16x8*)(xtR + (s)*2048 + 1024 + bofs);                 \
        BI0 = *(const bf16x8*)(xtI + (s)*2048 +        bofs);                 \
        BI1 = *(const bf16x8*)(xtI + (s)*2048 + 1024 + bofs);                 \
    } while (0)

#define COMP(s, BR0,BR1,BI0,BI1) do {                                         \
        const int j0_ = (s)*32 + jg*8;                                        \
        bf16x8 LR8 = *(const bf16x8*)&Lf[k_a][j0_];                           \
        bf16x8 LI8 = *(const bf16x8*)&Lf[4 + k_a][j0_];                       \
        bf16x8 AW8 = *(const bf16x8*)&awB[h_a][j0_];                          \
        bf16x8 Ar_, Ai_;                                                      \
        _Pragma("unroll")                                                     \
        for (int e_ = 0; e_ < 8; ++e_) {                                      \
            float awv = bfu2f((ushort)AW8[e_]);                               \
            Ar_[e_] = f2bfs(bfu2f((ushort)LR8[e_]) * awv);                    \
            Ai_[e_] = f2bfs(bfu2f((ushort)LI8[e_]) * awv);                    \
        }                                                                     \
        acc[0] = __builtin_amdgcn_mfma_f32_16x16x32_bf16(Ar_, BR0, acc[0],0,0,0); \
        acc[1] = __builtin_amdgcn_mfma_f32_16x16x32_bf16(Ar_, BR1, acc[1],0,0,0); \
        acc[2] = __builtin_amdgcn_mfma_f32_16x16x32_bf16(Ai_, BI0, acc[2],0,0,0); \
        acc[3] = __builtin_amdgcn_mfma_f32_16x16x32_bf16(Ai_, BI1, acc[3],0,0,0); \
        acc[4] = __builtin_amdgcn_mfma_f32_16x16x32_bf16(Ar_, BI0, acc[4],0,0,0); \
        acc[5] = __builtin_amdgcn_mfma_f32_16x16x32_bf16(Ar_, BI1, acc[5],0,0,0); \
        acc[6] = __builtin_amdgcn_mfma_f32_16x16x32_bf16(Ai_, BR0, acc[6],0,0,0); \
        acc[7] = __builtin_amdgcn_mfma_f32_16x16x32_bf16(Ai_, BR1, acc[7],0,0,0); \
    } while (0)

    {
        bf16x8 pR0,pR1,pI0,pI1, qR0,qR1,qI0,qI1;
        LB(0, pR0,pR1,pI0,pI1);
        LB(1, qR0,qR1,qI0,qI1);
        #pragma unroll
        for (int s = 0; s < 14; s += 2) {
            COMP(s,   pR0,pR1,pI0,pI1);
            LB(s+2,   pR0,pR1,pI0,pI1);
            COMP(s+1, qR0,qR1,qI0,qI1);
            LB(s+3,   qR0,qR1,qI0,qI1);
        }
        COMP(14, pR0,pR1,pI0,pI1);
        COMP(15, qR0,qR1,qI0,qI1);
    }
#undef LB
#undef COMP

    // ---- epilogue: wave owns full sums; normalize + write LX bf16 ----
    const int kk = t >> 4, lc = t & 15;
    char* lxp = wsB + LX_BASE + (size_t)bn*2048;
    #pragma unroll
    for (int ct = 0; ct < 2; ++ct) {
        const int c = ct*16 + lc;
        #pragma unroll
        for (int r = 0; r < 4; ++r) {   // r == h
            float iv = inv[r];
            float vr = (acc[0+ct][r] - acc[2+ct][r]) * iv;
            float vi = (acc[4+ct][r] + acc[6+ct][r]) * iv;
            *(ushort*)(lxp + r*512 +       kk*64 + c*2) = f2bfu(vr);
            *(ushort*)(lxp + r*512 + 256 + kk*64 + c*2) = f2bfu(vi);
        }
    }
}

// ---------------------------------------------------------------------------
// Out GEMM: Y[bn,o] = [LXr|LXi] @ Bre/Bim (K=256), + bias.
// grid 512 blocks (Mtile*4 + Nt) x 256 thr; wave = h.
// ---------------------------------------------------------------------------
__global__ __launch_bounds__(256) void out_gemm_kernel(
    const char* __restrict__ wsB,
    const float* __restrict__ bsr, const float* __restrict__ bsi,
    float* __restrict__ out)
{
    const int Mtile = blockIdx.x >> 2;
    const int Nt    = blockIdx.x & 3;
    const int t = threadIdx.x, l = t & 63, h = t >> 6;

    const char* abase = wsB + LX_BASE + ((size_t)(Mtile*16 + (l & 15)))*2048
                        + h*512 + (l >> 4)*16;
    f32x4 are = (f32x4){0.f,0.f,0.f,0.f};
    f32x4 aim = (f32x4){0.f,0.f,0.f,0.f};
    const size_t fbase = ((size_t)((h*4 + Nt)*8))*1024 + (size_t)l*16;
    const char* bre = wsB + BRE_BASE + fbase;
    const char* bim = wsB + BIM_BASE + fbase;
    #pragma unroll
    for (int s = 0; s < 8; ++s) {
        bf16x8 Af = *(const bf16x8*)(abase + s*64);
        bf16x8 Br = *(const bf16x8*)(bre + s*1024);
        bf16x8 Bi = *(const bf16x8*)(bim + s*1024);
        are = __builtin_amdgcn_mfma_f32_16x16x32_bf16(Af, Br, are, 0, 0, 0);
        aim = __builtin_amdgcn_mfma_f32_16x16x32_bf16(Af, Bi, aim, 0, 0, 0);
    }
    const int p = Nt*16 + (l & 15), o = p*4 + h;
    const float vbr = bsr[o], vbi = bsi[o];
    #pragma unroll
    for (int r = 0; r < 4; ++r) {
        int bn = Mtile*16 + (l >> 4)*4 + r;
        out[(size_t)bn*AOUT + o] = are[r] + vbr;
        out[(size_t)BB*NN*AOUT + (size_t)bn*AOUT + o] = aim[r] + vbi;
    }
}

// ---------------------------------------------------------------------------
extern "C" void kernel_launch(void* const* d_in, const int* in_sizes, int n_in,
                              void* d_out, int out_size, void* d_ws, size_t ws_size,
                              hipStream_t stream)
{
    const float* Xr  = (const float*)d_in[0];
    const float* Xi  = (const float*)d_in[1];
    const float* Lr  = (const float*)d_in[2];
    const float* Li  = (const float*)d_in[3];
    const float* Wr  = (const float*)d_in[4];
    const float* Wi  = (const float*)d_in[5];
    const float* AWr = (const float*)d_in[6];
    const float* AWi = (const float*)d_in[7];
    const float* abr = (const float*)d_in[8];
    const float* abi = (const float*)d_in[9];
    const float* par = (const float*)d_in[10];
    const float* pai = (const float*)d_in[11];
    const float* bsr = (const float*)d_in[12];
    const float* bsi = (const float*)d_in[13];
    float* ws  = (float*)d_ws;
    char*  wsB = (char*)d_ws;
    float* out = (float*)d_out;

    hipLaunchKernelGGL(prep_kernel, dim3(96), dim3(256), 0, stream,
                       Xr, Xi, AWr, AWi, Wr, Wi, ws, wsB);
    hipLaunchKernelGGL(cheb_main_kernel, dim3(BB*NN), dim3(64), 0, stream,
                       Lr, Li, abr, abi, par, pai, ws, wsB);
    hipLaunchKernelGGL(out_gemm_kernel, dim3(512), dim3(256), 0, stream,
                       wsB, bsr, bsi, out);
}